// Round 7
// baseline (197.202 us; speedup 1.0000x reference)
//
#include <hip/hip_runtime.h>

// ROSA 1-bit, B=4, T=2048, C=128 (512 sequences).
// Round 7: round-6 structure (proven absmax 0) with the per-bit run/max
// recurrence split into FOUR independent 8-bit chains per word. Carries into
// bits 8/16/24 are computed directly from m and inc via capped-clz:
//   u_k = clz(((~m)<<(32-k)) | (1<<(k... guard))) = min(trailing-ones(m[k-1:0]), k)
//   s_k = u_k + (u_k==k ? inc : 0)         (exact; deep carries live in inc)
// This turns the round-6 serial 32x{add->bfi} dependency chain (~256 cyc
// latency/step, suspected source of ~40% issue-slot stalls) into 4-way ILP.
// Quad stays 4 VALU/bit; seeds/masks/merge/k_bits/k_dec unchanged.

#define TT 2048
#define CC 128
#define NW 64
#define NSEQ 512
#define SBITS_WORDS (NSEQ * NW)       // 128 KB
#define RES_WORDS (NSEQ * TT)         // 4 MB, layout [q][i]

// ---------------- kernel 0: pack bits ----------------
__global__ void k_bits(const float* __restrict__ x, unsigned* __restrict__ sbits)
{
    const int b = blockIdx.x >> 6;
    const int w = blockIdx.x & 63;
    const int t = threadIdx.x;
    __shared__ unsigned char sbyt[32 * 132];

    #pragma unroll
    for (int r = 0; r < 16; ++r) {
        const int e  = t + (r << 8);
        const int ii = e >> 7;
        const int c  = e & 127;
        const float v = x[((size_t)(b * TT + (w << 5) + ii)) * CC + c];
        sbyt[ii * 132 + c] = (v > 0.0f) ? 1u : 0u;
    }
    __syncthreads();

    if (t < CC) {
        unsigned word = 0u;
        #pragma unroll
        for (int ii = 0; ii < 32; ++ii)
            word |= (unsigned)(sbyt[ii * 132 + t] & 1u) << ii;
        sbits[((b << 7) | t) * NW + w] = word;
    }
}

// per-bit quad: keep = sext(bit bb of m); pkv = keep ? pkv+0x800 : dcode;
// lmax = max(lmax, pkv). 4 VALU.
#define QUAD(PK, LM, BB)                                           \
    {                                                              \
        unsigned keep_;                                            \
        asm("v_bfe_i32 %0, %3, %4, 1\n\t"                          \
            "v_add_u32 %1, 0x800, %1\n\t"                          \
            "v_bfi_b32 %1, %0, %1, %5\n\t"                         \
            "v_max_u32 %2, %2, %1"                                 \
            : "=&v"(keep_), "+v"(PK), "+v"(LM)                     \
            : "v"(m), "n"(BB), "v"(dcode));                        \
    }

// ---------------- kernel 1: tiled diagonal DP ----------------
__global__ __launch_bounds__(256, 4) void k_dp2(
    const unsigned* __restrict__ sbits, unsigned* __restrict__ res)
{
    const int u = blockIdx.x;            // 0..35 (triangular (k, chunk))
    const int q = blockIdx.y;            // sequence = b*128 + c
    int k = 0;
    #pragma unroll
    for (int kk = 1; kk < 8; ++kk) if (u >= (kk * (kk + 1)) / 2) k = kk;
    const int chunk = u - (k * (k + 1)) / 2;
    const int D0 = 1 + (chunk << 8);

    const int tid  = threadIdx.x;
    const int lane = tid & 63;
    const int wv   = tid >> 6;
    const int g    = lane >> 3;          // stream in wave
    const int lm   = lane & 7;           // lane within stream
    const int wB   = k << 3;
    const int wloc = wB + lm;            // fixed output word of this lane
    const int kb   = k << 8;

    __shared__ unsigned pad[128];        // [0..63]=0, [64+w]=word w
    __shared__ unsigned seedl[256];      // incoming run at tile base per diagonal
    __shared__ unsigned wres[4][8][33];

    if (tid < 64) pad[tid] = 0u;
    else if (tid < 128) pad[tid] = sbits[q * NW + (tid - 64)];
    __syncthreads();

    // --- seed precompute: thread t -> diagonal D0+t ---
    {
        const int d = D0 + tid;
        unsigned acc = 0u;
        if (d < kb) {
            const int dw = d >> 5, dr = d & 31;
            for (int w = wB - 1; w >= 0; --w) {
                const int sw = w - dw;
                const unsigned u0 = pad[64 + sw];
                const unsigned u1 = pad[63 + sw];
                const unsigned shw = dr ? ((u0 << dr) | (u1 >> (32 - dr))) : u0;
                const unsigned ew = (sw > 0) ? 0xFFFFFFFFu
                                  : ((sw == 0) ? (0xFFFFFFFFu << dr) : 0u);
                const unsigned mw = (~(pad[64 + w] ^ shw)) & ew;
                const unsigned t2 = (mw == 0xFFFFFFFFu) ? 32u
                                  : (unsigned)__builtin_clz(~mw);
                acc += t2;
                if (t2 < 32u) break;
            }
        }
        seedl[tid] = acc;
    }
    __syncthreads();

    const unsigned a = pad[64 + wloc];

    unsigned lmax[32];
    #pragma unroll
    for (int bb = 0; bb < 32; ++bb) lmax[bb] = 0u;

    #pragma unroll
    for (int it = 0; it < 8; ++it) {
        const int d  = D0 + (it << 5) + (wv << 3) + g;
        const int dw = d >> 5;
        const int dr = d & 31;
        const unsigned dcode = (unsigned)(TT - d);   // 0 at d==2048 (em=0 then)

        const int s = wloc - dw;
        const unsigned b0 = pad[64 + s];
        const unsigned b1 = pad[63 + s];
        const unsigned sh = dr ? ((b0 << dr) | (b1 >> (32 - dr))) : b0;
        const unsigned em = (s > 0) ? 0xFFFFFFFFu
                          : ((s == 0) ? (0xFFFFFFFFu << dr) : 0u);
        const unsigned m = (~(a ^ sh)) & em;

        // --- incoming run: seed for stream heads, clz fast path otherwise ---
        const unsigned seedv = seedl[(it << 5) + (wv << 3) + g];
        const unsigned pm = (unsigned)__shfl_up((int)m, 1, 64);
        const unsigned lead = (unsigned)__builtin_clz(~pm | 1u);
        unsigned inc = (lm == 0) ? seedv : lead;

        // exact rare fallback: some lane's previous word fully matched
        if (__builtin_expect(
                __ballot((lm > 0) && (pm == 0xFFFFFFFFu)) != 0ULL, 0)) {
            if ((lm > 0) && (pm == 0xFFFFFFFFu)) {
                unsigned acc = 0u;
                int w;
                for (w = wloc - 1; w >= wB; --w) {
                    const int sw = w - dw;
                    const unsigned u0 = pad[64 + sw];
                    const unsigned u1 = pad[63 + sw];
                    const unsigned shw = dr ? ((u0 << dr) | (u1 >> (32 - dr))) : u0;
                    const unsigned ew = (sw > 0) ? 0xFFFFFFFFu
                                      : ((sw == 0) ? (0xFFFFFFFFu << dr) : 0u);
                    const unsigned mw = (~(pad[64 + w] ^ shw)) & ew;
                    const unsigned t2 = (mw == 0xFFFFFFFFu) ? 32u
                                      : (unsigned)__builtin_clz(~mw);
                    acc += t2;
                    if (t2 < 32u) break;
                }
                if (w < wB) acc += seedv;
                inc = acc;
            }
        }

        // --- carries into bits 8/16/24 via capped clz (exact) ---
        const unsigned nm = ~m;
        const unsigned u8  = (unsigned)__builtin_clz((nm << 24) | 0x00800000u);
        const unsigned u16 = (unsigned)__builtin_clz((nm << 16) | 0x00008000u);
        const unsigned u24 = (unsigned)__builtin_clz((nm <<  8) | 0x00000080u);
        const unsigned s8  = u8  + ((u8  == 8u)  ? inc : 0u);
        const unsigned s16 = u16 + ((u16 == 16u) ? inc : 0u);
        const unsigned s24 = u24 + ((u24 == 24u) ? inc : 0u);

        // --- four independent 8-bit chains, interleaved for ILP ---
        unsigned pk0 = (inc << 11) | dcode;
        unsigned pk1 = (s8  << 11) | dcode;
        unsigned pk2 = (s16 << 11) | dcode;
        unsigned pk3 = (s24 << 11) | dcode;
        #pragma unroll
        for (int bb = 0; bb < 8; ++bb) {
            QUAD(pk0, lmax[bb],      bb);
            QUAD(pk1, lmax[8 + bb],  8 + bb);
            QUAD(pk2, lmax[16 + bb], 16 + bb);
            QUAD(pk3, lmax[24 + bb], 24 + bb);
        }
    }

    // --- reduce the 8 streams sharing each word ---
    #pragma unroll
    for (int bb = 0; bb < 32; ++bb) {
        unsigned v = lmax[bb];
        v = max(v, (unsigned)__shfl_xor((int)v, 8, 64));
        v = max(v, (unsigned)__shfl_xor((int)v, 16, 64));
        v = max(v, (unsigned)__shfl_xor((int)v, 32, 64));
        lmax[bb] = v;
    }
    if (lane < 8) {
        #pragma unroll
        for (int bb = 0; bb < 32; ++bb) wres[wv][lane][bb] = lmax[bb];
    }
    __syncthreads();

    // --- block merge + contiguous atomics into res[q][i] ---
    {
        const int lw = tid >> 5, bb = tid & 31;
        const unsigned v = max(max(wres[0][lw][bb], wres[1][lw][bb]),
                               max(wres[2][lw][bb], wres[3][lw][bb]));
        if (v >> 11) {
            const int i = ((wB + lw) << 5) + bb;
            atomicMax(&res[(size_t)q * TT + i], v);
        }
    }
}

// ---------------- kernel 2: decode (LDS transpose) ----------------
__global__ void k_dec(const unsigned* __restrict__ sbits,
                      const unsigned* __restrict__ res,
                      const float* __restrict__ emb0,
                      const float* __restrict__ emb1,
                      float* __restrict__ out)
{
    const int b  = blockIdx.y;
    const int i0 = blockIdx.x << 4;
    const int t  = threadIdx.x;
    __shared__ float trans[16][CC + 4];

    const int c  = t >> 1;
    const int q8 = (t & 1) << 3;
    const unsigned* rp = res + ((size_t)((b << 7) | c) * TT) + i0 + q8;
    const unsigned* bw = sbits + ((size_t)((b << 7) | c)) * NW;
    const float e0 = emb0[c], e1 = emb1[c];

    #pragma unroll
    for (int jj = 0; jj < 8; ++jj) {
        const unsigned v = rp[jj];
        const int i = i0 + q8 + jj;
        float val = 0.0f;
        if (v >> 11) {
            const int d   = TT - (int)(v & 2047u);
            const int e1p = i - d + 1;
            val = ((bw[e1p >> 5] >> (e1p & 31)) & 1u) ? e1 : e0;
        }
        trans[q8 + jj][c] = val;
    }
    __syncthreads();

    const int ii = t >> 4;
    const int c0 = (t & 15) << 3;
    float4 w0 = *(const float4*)&trans[ii][c0];
    float4 w1 = *(const float4*)&trans[ii][c0 + 4];
    float* op = out + ((size_t)(b * TT + i0 + ii)) * CC + c0;
    *(float4*)op       = w0;
    *(float4*)(op + 4) = w1;
}

extern "C" void kernel_launch(void* const* d_in, const int* in_sizes, int n_in,
                              void* d_out, int out_size, void* d_ws, size_t ws_size,
                              hipStream_t stream)
{
    const float* x    = (const float*)d_in[0];
    const float* emb0 = (const float*)d_in[1];
    const float* emb1 = (const float*)d_in[2];
    float* out        = (float*)d_out;

    unsigned* sbits = (unsigned*)d_ws;                    // 128 KB
    unsigned* res   = (unsigned*)d_ws + SBITS_WORDS;      // 4 MB

    hipMemsetAsync((void*)res, 0, (size_t)RES_WORDS * 4, stream);
    k_bits<<<dim3(4 * 64), dim3(256), 0, stream>>>(x, sbits);
    k_dp2<<<dim3(36, NSEQ), dim3(256), 0, stream>>>(sbits, res);
    k_dec<<<dim3(TT / 16, 4), dim3(256), 0, stream>>>(sbits, res, emb0, emb1, out);
}

// Round 8
// 190.513 us; speedup vs baseline: 1.0351x; 1.0351x over previous
//
#include <hip/hip_runtime.h>

// ROSA 1-bit, B=4, T=2048, C=128 (512 sequences).
// Round 8: round-6 structure (proven absmax 0) with the per-bit quad loop
// fused into two 16-bit MEGA-ASM blocks that name lmax[0..15] / lmax[16..31]
// as simultaneous "+v" operands. Theory: rounds 4-7 show time ~ 2x static
// inst at VALUBusy~100% with VGPR_Count=36 (< lmax[32]) => compiler homes
// lmax in AGPRs and brackets every 4-inst quad with v_accvgpr_read/write
// (6 inst/bit effective). Forcing 16 lmax into arch VGPRs per block removes
// the shuttle. 0x800 literal -> SGPR (kills 32 literal dwords/step).

#define TT 2048
#define CC 128
#define NW 64
#define NSEQ 512
#define SBITS_WORDS (NSEQ * NW)       // 128 KB
#define RES_WORDS (NSEQ * TT)         // 4 MB, layout [q][i]

// ---------------- kernel 0: pack bits ----------------
__global__ void k_bits(const float* __restrict__ x, unsigned* __restrict__ sbits)
{
    const int b = blockIdx.x >> 6;
    const int w = blockIdx.x & 63;
    const int t = threadIdx.x;
    __shared__ unsigned char sbyt[32 * 132];

    #pragma unroll
    for (int r = 0; r < 16; ++r) {
        const int e  = t + (r << 8);
        const int ii = e >> 7;
        const int c  = e & 127;
        const float v = x[((size_t)(b * TT + (w << 5) + ii)) * CC + c];
        sbyt[ii * 132 + c] = (v > 0.0f) ? 1u : 0u;
    }
    __syncthreads();

    if (t < CC) {
        unsigned word = 0u;
        #pragma unroll
        for (int ii = 0; ii < 32; ++ii)
            word |= (unsigned)(sbyt[ii * 132 + t] & 1u) << ii;
        sbits[((b << 7) | t) * NW + w] = word;
    }
}

// one per-bit quad inside the mega-asm:
// pkv += 0x800 (SGPR); keep = sext(m[BB]); pkv = keep ? pkv : dcode;
// lmax[i] = max(lmax[i], pkv).   %0=tmp %1=pkv %18=m %19=dcode %20=0x800
#define QB(BB, LX)                                  \
    "v_add_u32 %1, %20, %1\n\t"                     \
    "v_bfe_i32 %0, %18, " BB ", 1\n\t"              \
    "v_bfi_b32 %1, %0, %1, %19\n\t"                 \
    "v_max_u32 " LX ", " LX ", %1\n\t"

// ---------------- kernel 1: tiled diagonal DP ----------------
__global__ __launch_bounds__(256, 4) void k_dp2(
    const unsigned* __restrict__ sbits, unsigned* __restrict__ res)
{
    const int u = blockIdx.x;            // 0..35 (triangular (k, chunk))
    const int q = blockIdx.y;            // sequence = b*128 + c
    int k = 0;
    #pragma unroll
    for (int kk = 1; kk < 8; ++kk) if (u >= (kk * (kk + 1)) / 2) k = kk;
    const int chunk = u - (k * (k + 1)) / 2;
    const int D0 = 1 + (chunk << 8);

    const int tid  = threadIdx.x;
    const int lane = tid & 63;
    const int wv   = tid >> 6;
    const int g    = lane >> 3;          // stream in wave
    const int lm   = lane & 7;           // lane within stream
    const int wB   = k << 3;
    const int wloc = wB + lm;            // fixed output word of this lane
    const int kb   = k << 8;

    __shared__ unsigned pad[128];        // [0..63]=0, [64+w]=word w
    __shared__ unsigned seedl[256];      // incoming run at tile base per diagonal
    __shared__ unsigned wres[4][8][33];

    if (tid < 64) pad[tid] = 0u;
    else if (tid < 128) pad[tid] = sbits[q * NW + (tid - 64)];
    __syncthreads();

    // --- seed precompute: thread t -> diagonal D0+t ---
    {
        const int d = D0 + tid;
        unsigned acc = 0u;
        if (d < kb) {
            const int dw = d >> 5, dr = d & 31;
            for (int w = wB - 1; w >= 0; --w) {
                const int sw = w - dw;
                const unsigned u0 = pad[64 + sw];
                const unsigned u1 = pad[63 + sw];
                const unsigned shw = dr ? ((u0 << dr) | (u1 >> (32 - dr))) : u0;
                const unsigned ew = (sw > 0) ? 0xFFFFFFFFu
                                  : ((sw == 0) ? (0xFFFFFFFFu << dr) : 0u);
                const unsigned mw = (~(pad[64 + w] ^ shw)) & ew;
                const unsigned t2 = (mw == 0xFFFFFFFFu) ? 32u
                                  : (unsigned)__builtin_clz(~mw);
                acc += t2;
                if (t2 < 32u) break;
            }
        }
        seedl[tid] = acc;
    }
    __syncthreads();

    const unsigned a = pad[64 + wloc];

    unsigned lmax[32];
    #pragma unroll
    for (int bb = 0; bb < 32; ++bb) lmax[bb] = 0u;

    #pragma unroll
    for (int it = 0; it < 8; ++it) {
        const int d  = D0 + (it << 5) + (wv << 3) + g;
        const int dw = d >> 5;
        const int dr = d & 31;
        const unsigned dcode = (unsigned)(TT - d);   // 0 at d==2048 (em=0 then)

        const int s = wloc - dw;
        const unsigned b0 = pad[64 + s];
        const unsigned b1 = pad[63 + s];
        const unsigned sh = dr ? ((b0 << dr) | (b1 >> (32 - dr))) : b0;
        const unsigned em = (s > 0) ? 0xFFFFFFFFu
                          : ((s == 0) ? (0xFFFFFFFFu << dr) : 0u);
        const unsigned m = (~(a ^ sh)) & em;

        // --- incoming run: seed for stream heads, clz fast path otherwise ---
        const unsigned seedv = seedl[(it << 5) + (wv << 3) + g];
        const unsigned pm = (unsigned)__shfl_up((int)m, 1, 64);
        const unsigned lead = (unsigned)__builtin_clz(~pm | 1u);
        unsigned inc = (lm == 0) ? seedv : lead;

        // exact rare fallback: some lane's previous word fully matched
        if (__builtin_expect(
                __ballot((lm > 0) && (pm == 0xFFFFFFFFu)) != 0ULL, 0)) {
            if ((lm > 0) && (pm == 0xFFFFFFFFu)) {
                unsigned acc = 0u;
                int w;
                for (w = wloc - 1; w >= wB; --w) {
                    const int sw = w - dw;
                    const unsigned u0 = pad[64 + sw];
                    const unsigned u1 = pad[63 + sw];
                    const unsigned shw = dr ? ((u0 << dr) | (u1 >> (32 - dr))) : u0;
                    const unsigned ew = (sw > 0) ? 0xFFFFFFFFu
                                      : ((sw == 0) ? (0xFFFFFFFFu << dr) : 0u);
                    const unsigned mw = (~(pad[64 + w] ^ shw)) & ew;
                    const unsigned t2 = (mw == 0xFFFFFFFFu) ? 32u
                                      : (unsigned)__builtin_clz(~mw);
                    acc += t2;
                    if (t2 < 32u) break;
                }
                if (w < wB) acc += seedv;
                inc = acc;
            }
        }

        // --- per-bit run + packed max: two 16-bit mega-asm blocks ---
        unsigned pkv = (inc << 11) | dcode;
        unsigned tmp;
        asm(QB("0",  "%2")  QB("1",  "%3")  QB("2",  "%4")  QB("3",  "%5")
            QB("4",  "%6")  QB("5",  "%7")  QB("6",  "%8")  QB("7",  "%9")
            QB("8",  "%10") QB("9",  "%11") QB("10", "%12") QB("11", "%13")
            QB("12", "%14") QB("13", "%15") QB("14", "%16") QB("15", "%17")
            : "=&v"(tmp), "+v"(pkv),
              "+v"(lmax[0]),  "+v"(lmax[1]),  "+v"(lmax[2]),  "+v"(lmax[3]),
              "+v"(lmax[4]),  "+v"(lmax[5]),  "+v"(lmax[6]),  "+v"(lmax[7]),
              "+v"(lmax[8]),  "+v"(lmax[9]),  "+v"(lmax[10]), "+v"(lmax[11]),
              "+v"(lmax[12]), "+v"(lmax[13]), "+v"(lmax[14]), "+v"(lmax[15])
            : "v"(m), "v"(dcode), "s"(2048u));
        asm(QB("16", "%2")  QB("17", "%3")  QB("18", "%4")  QB("19", "%5")
            QB("20", "%6")  QB("21", "%7")  QB("22", "%8")  QB("23", "%9")
            QB("24", "%10") QB("25", "%11") QB("26", "%12") QB("27", "%13")
            QB("28", "%14") QB("29", "%15") QB("30", "%16") QB("31", "%17")
            : "=&v"(tmp), "+v"(pkv),
              "+v"(lmax[16]), "+v"(lmax[17]), "+v"(lmax[18]), "+v"(lmax[19]),
              "+v"(lmax[20]), "+v"(lmax[21]), "+v"(lmax[22]), "+v"(lmax[23]),
              "+v"(lmax[24]), "+v"(lmax[25]), "+v"(lmax[26]), "+v"(lmax[27]),
              "+v"(lmax[28]), "+v"(lmax[29]), "+v"(lmax[30]), "+v"(lmax[31])
            : "v"(m), "v"(dcode), "s"(2048u));
    }

    // --- reduce the 8 streams sharing each word ---
    #pragma unroll
    for (int bb = 0; bb < 32; ++bb) {
        unsigned v = lmax[bb];
        v = max(v, (unsigned)__shfl_xor((int)v, 8, 64));
        v = max(v, (unsigned)__shfl_xor((int)v, 16, 64));
        v = max(v, (unsigned)__shfl_xor((int)v, 32, 64));
        lmax[bb] = v;
    }
    if (lane < 8) {
        #pragma unroll
        for (int bb = 0; bb < 32; ++bb) wres[wv][lane][bb] = lmax[bb];
    }
    __syncthreads();

    // --- block merge + contiguous atomics into res[q][i] ---
    {
        const int lw = tid >> 5, bb = tid & 31;
        const unsigned v = max(max(wres[0][lw][bb], wres[1][lw][bb]),
                               max(wres[2][lw][bb], wres[3][lw][bb]));
        if (v >> 11) {
            const int i = ((wB + lw) << 5) + bb;
            atomicMax(&res[(size_t)q * TT + i], v);
        }
    }
}

// ---------------- kernel 2: decode (LDS transpose) ----------------
__global__ void k_dec(const unsigned* __restrict__ sbits,
                      const unsigned* __restrict__ res,
                      const float* __restrict__ emb0,
                      const float* __restrict__ emb1,
                      float* __restrict__ out)
{
    const int b  = blockIdx.y;
    const int i0 = blockIdx.x << 4;
    const int t  = threadIdx.x;
    __shared__ float trans[16][CC + 4];

    const int c  = t >> 1;
    const int q8 = (t & 1) << 3;
    const unsigned* rp = res + ((size_t)((b << 7) | c) * TT) + i0 + q8;
    const unsigned* bw = sbits + ((size_t)((b << 7) | c)) * NW;
    const float e0 = emb0[c], e1 = emb1[c];

    #pragma unroll
    for (int jj = 0; jj < 8; ++jj) {
        const unsigned v = rp[jj];
        const int i = i0 + q8 + jj;
        float val = 0.0f;
        if (v >> 11) {
            const int d   = TT - (int)(v & 2047u);
            const int e1p = i - d + 1;
            val = ((bw[e1p >> 5] >> (e1p & 31)) & 1u) ? e1 : e0;
        }
        trans[q8 + jj][c] = val;
    }
    __syncthreads();

    const int ii = t >> 4;
    const int c0 = (t & 15) << 3;
    float4 w0 = *(const float4*)&trans[ii][c0];
    float4 w1 = *(const float4*)&trans[ii][c0 + 4];
    float* op = out + ((size_t)(b * TT + i0 + ii)) * CC + c0;
    *(float4*)op       = w0;
    *(float4*)(op + 4) = w1;
}

extern "C" void kernel_launch(void* const* d_in, const int* in_sizes, int n_in,
                              void* d_out, int out_size, void* d_ws, size_t ws_size,
                              hipStream_t stream)
{
    const float* x    = (const float*)d_in[0];
    const float* emb0 = (const float*)d_in[1];
    const float* emb1 = (const float*)d_in[2];
    float* out        = (float*)d_out;

    unsigned* sbits = (unsigned*)d_ws;                    // 128 KB
    unsigned* res   = (unsigned*)d_ws + SBITS_WORDS;      // 4 MB

    hipMemsetAsync((void*)res, 0, (size_t)RES_WORDS * 4, stream);
    k_bits<<<dim3(4 * 64), dim3(256), 0, stream>>>(x, sbits);
    k_dp2<<<dim3(36, NSEQ), dim3(256), 0, stream>>>(sbits, res);
    k_dec<<<dim3(TT / 16, 4), dim3(256), 0, stream>>>(sbits, res, emb0, emb1, out);
}

// Round 9
// 172.190 us; speedup vs baseline: 1.1453x; 1.1064x over previous
//
#include <hip/hip_runtime.h>

// ROSA 1-bit, B=4, T=2048, C=128 (512 sequences).
// Round 9: 16-bit SWAR inner loop via VOP3P packed ops. Per lane, word-bits
// j and j+16 live in the two halves of one register; per-it value is
// r' = (run<<3)|(7-it) (run<=2047 fits 14 bits; max picks max run then
// min it = min d = most recent — exact). Chain split at bit 16, entry carry
// via capped clz (round-7 s16 trick, exact incl. rare fallback).
// Per packed step: pk_ashr(sign->mask) / pk_add / bfi / pk_max / pk_shl
// = 5 inst per 2 cells (was 4/cell), accumulator state 16 regs (was 32)
// -> fits arch VGPRs, kills the suspected AGPR shuttle.
// Full (run<<11)|dcode expansion once per block in the epilogue.

#define TT 2048
#define CC 128
#define NW 64
#define NSEQ 512
#define SBITS_WORDS (NSEQ * NW)       // 128 KB
#define RES_WORDS (NSEQ * TT)         // 4 MB, layout [q][i]

// ---------------- kernel 0: pack bits ----------------
__global__ void k_bits(const float* __restrict__ x, unsigned* __restrict__ sbits)
{
    const int b = blockIdx.x >> 6;
    const int w = blockIdx.x & 63;
    const int t = threadIdx.x;
    __shared__ unsigned char sbyt[32 * 132];

    #pragma unroll
    for (int r = 0; r < 16; ++r) {
        const int e  = t + (r << 8);
        const int ii = e >> 7;
        const int c  = e & 127;
        const float v = x[((size_t)(b * TT + (w << 5) + ii)) * CC + c];
        sbyt[ii * 132 + c] = (v > 0.0f) ? 1u : 0u;
    }
    __syncthreads();

    if (t < CC) {
        unsigned word = 0u;
        #pragma unroll
        for (int ii = 0; ii < 32; ++ii)
            word |= (unsigned)(sbyt[ii * 132 + t] & 1u) << ii;
        sbits[((b << 7) | t) * NW + w] = word;
    }
}

// one packed step: process word-bits (j, 16+j) for this it.
// %0=tm %1=rp %2=mmr  %3..%18=lmaxp[0..15]  %19=c15 %20=c8 %21=c1 %22=itc2
#define PJ(LX)                                     \
    "v_pk_ashrrev_i16 %0, %19, %2\n\t"             \
    "v_pk_add_u16 %1, %1, %20\n\t"                 \
    "v_bfi_b32 %1, %0, %1, %22\n\t"                \
    "v_pk_max_u16 " LX ", " LX ", %1\n\t"          \
    "v_pk_lshlrev_b16 %2, %21, %2\n\t"

// ---------------- kernel 1: tiled diagonal DP (packed) ----------------
__global__ __launch_bounds__(256, 4) void k_dp2(
    const unsigned* __restrict__ sbits, unsigned* __restrict__ res)
{
    const int u = blockIdx.x;            // 0..35 (triangular (k, chunk))
    const int q = blockIdx.y;            // sequence = b*128 + c
    int k = 0;
    #pragma unroll
    for (int kk = 1; kk < 8; ++kk) if (u >= (kk * (kk + 1)) / 2) k = kk;
    const int chunk = u - (k * (k + 1)) / 2;
    const int D0 = 1 + (chunk << 8);

    const int tid  = threadIdx.x;
    const int lane = tid & 63;
    const int wv   = tid >> 6;
    const int g    = lane >> 3;          // stream in wave
    const int lm   = lane & 7;           // lane within stream
    const int wB   = k << 3;
    const int wloc = wB + lm;            // fixed output word of this lane
    const int kb   = k << 8;

    __shared__ unsigned pad[128];        // [0..63]=0, [64+w]=word w
    __shared__ unsigned seedl[256];      // incoming run at tile base per diagonal
    __shared__ unsigned wres[4][8][33];

    if (tid < 64) pad[tid] = 0u;
    else if (tid < 128) pad[tid] = sbits[q * NW + (tid - 64)];
    __syncthreads();

    // --- seed precompute: thread t -> diagonal D0+t ---
    {
        const int d = D0 + tid;
        unsigned acc = 0u;
        if (d < kb) {
            const int dw = d >> 5, dr = d & 31;
            for (int w = wB - 1; w >= 0; --w) {
                const int sw = w - dw;
                const unsigned u0 = pad[64 + sw];
                const unsigned u1 = pad[63 + sw];
                const unsigned shw = dr ? ((u0 << dr) | (u1 >> (32 - dr))) : u0;
                const unsigned ew = (sw > 0) ? 0xFFFFFFFFu
                                  : ((sw == 0) ? (0xFFFFFFFFu << dr) : 0u);
                const unsigned mw = (~(pad[64 + w] ^ shw)) & ew;
                const unsigned t2 = (mw == 0xFFFFFFFFu) ? 32u
                                  : (unsigned)__builtin_clz(~mw);
                acc += t2;
                if (t2 < 32u) break;
            }
        }
        seedl[tid] = acc;
    }
    __syncthreads();

    const unsigned a = pad[64 + wloc];

    unsigned lmaxp[16];
    #pragma unroll
    for (int j = 0; j < 16; ++j) lmaxp[j] = 0u;

    const unsigned c15v = 0x000F000Fu;
    const unsigned c8v  = 0x00080008u;
    const unsigned c1v  = 0x00010001u;

    #pragma unroll
    for (int it = 0; it < 8; ++it) {
        const int d  = D0 + (it << 5) + (wv << 3) + g;
        const int dw = d >> 5;
        const int dr = d & 31;

        const int s = wloc - dw;
        const unsigned b0 = pad[64 + s];
        const unsigned b1 = pad[63 + s];
        const unsigned sh = dr ? ((b0 << dr) | (b1 >> (32 - dr))) : b0;
        const unsigned em = (s > 0) ? 0xFFFFFFFFu
                          : ((s == 0) ? (0xFFFFFFFFu << dr) : 0u);
        const unsigned m = (~(a ^ sh)) & em;

        // --- incoming run: seed for stream heads, clz fast path otherwise ---
        const unsigned seedv = seedl[(it << 5) + (wv << 3) + g];
        const unsigned pm = (unsigned)__shfl_up((int)m, 1, 64);
        const unsigned lead = (unsigned)__builtin_clz(~pm | 1u);
        unsigned inc = (lm == 0) ? seedv : lead;

        // exact rare fallback: some lane's previous word fully matched
        if (__builtin_expect(
                __ballot((lm > 0) && (pm == 0xFFFFFFFFu)) != 0ULL, 0)) {
            if ((lm > 0) && (pm == 0xFFFFFFFFu)) {
                unsigned acc = 0u;
                int w;
                for (w = wloc - 1; w >= wB; --w) {
                    const int sw = w - dw;
                    const unsigned u0 = pad[64 + sw];
                    const unsigned u1 = pad[63 + sw];
                    const unsigned shw = dr ? ((u0 << dr) | (u1 >> (32 - dr))) : u0;
                    const unsigned ew = (sw > 0) ? 0xFFFFFFFFu
                                      : ((sw == 0) ? (0xFFFFFFFFu << dr) : 0u);
                    const unsigned mw = (~(pad[64 + w] ^ shw)) & ew;
                    const unsigned t2 = (mw == 0xFFFFFFFFu) ? 32u
                                      : (unsigned)__builtin_clz(~mw);
                    acc += t2;
                    if (t2 < 32u) break;
                }
                if (w < wB) acc += seedv;
                inc = acc;
            }
        }

        // --- chain-B (bits 16..31) entry: run into bit 16, capped clz ---
        const unsigned nm   = ~m;
        const unsigned u16c = (unsigned)__builtin_clz((nm << 16) | 0x8000u);
        const unsigned s16  = u16c + ((u16c == 16u) ? inc : 0u);

        const unsigned itc  = 7u - (unsigned)it;
        const unsigned itc2 = itc * 0x10001u;
        unsigned rp = ((inc << 3) | itc) | (((s16 << 3) | itc) << 16);

        // mmr: chain A (m[15:0]) in lo half, chain B (m[31:16]) in hi half,
        // bit j at the sign position of each half after j left-shifts.
        const unsigned mr  = __builtin_bitreverse32(m);
        unsigned mmr = (mr >> 16) | (mr << 16);

        unsigned tm;
        asm(PJ("%3")  PJ("%4")  PJ("%5")  PJ("%6")
            PJ("%7")  PJ("%8")  PJ("%9")  PJ("%10")
            PJ("%11") PJ("%12") PJ("%13") PJ("%14")
            PJ("%15") PJ("%16") PJ("%17") PJ("%18")
            : "=&v"(tm), "+v"(rp), "+v"(mmr),
              "+v"(lmaxp[0]),  "+v"(lmaxp[1]),  "+v"(lmaxp[2]),  "+v"(lmaxp[3]),
              "+v"(lmaxp[4]),  "+v"(lmaxp[5]),  "+v"(lmaxp[6]),  "+v"(lmaxp[7]),
              "+v"(lmaxp[8]),  "+v"(lmaxp[9]),  "+v"(lmaxp[10]), "+v"(lmaxp[11]),
              "+v"(lmaxp[12]), "+v"(lmaxp[13]), "+v"(lmaxp[14]), "+v"(lmaxp[15])
            : "v"(c15v), "v"(c8v), "v"(c1v), "v"(itc2));
    }

    // --- epilogue: expand packed (run<<3|itc) -> (run<<11)|dcode ---
    // dcode = 2048 - d = Kp + (itc<<5), Kp = 2048 - D0 - (wv<<3) - g - 224.
    unsigned lm32[32];
    const unsigned Kp = 2048u - (unsigned)(D0 + (wv << 3) + g) - 224u;
    #pragma unroll
    for (int j = 0; j < 16; ++j) {
        const unsigned v  = lmaxp[j];
        const unsigned lo = v & 0xFFFFu;
        const unsigned hi = v >> 16;
        lm32[j]      = ((lo & 0xFFF8u) << 8) + ((lo & 7u) << 5) + Kp;
        lm32[16 + j] = ((hi & 0xFFF8u) << 8) + ((hi & 7u) << 5) + Kp;
    }

    // --- reduce the 8 streams sharing each word ---
    #pragma unroll
    for (int bb = 0; bb < 32; ++bb) {
        unsigned v = lm32[bb];
        v = max(v, (unsigned)__shfl_xor((int)v, 8, 64));
        v = max(v, (unsigned)__shfl_xor((int)v, 16, 64));
        v = max(v, (unsigned)__shfl_xor((int)v, 32, 64));
        lm32[bb] = v;
    }
    if (lane < 8) {
        #pragma unroll
        for (int bb = 0; bb < 32; ++bb) wres[wv][lane][bb] = lm32[bb];
    }
    __syncthreads();

    // --- block merge + contiguous atomics into res[q][i] ---
    {
        const int lw = tid >> 5, bb = tid & 31;
        const unsigned v = max(max(wres[0][lw][bb], wres[1][lw][bb]),
                               max(wres[2][lw][bb], wres[3][lw][bb]));
        if (v >> 11) {
            const int i = ((wB + lw) << 5) + bb;
            atomicMax(&res[(size_t)q * TT + i], v);
        }
    }
}

// ---------------- kernel 2: decode (LDS transpose) ----------------
__global__ void k_dec(const unsigned* __restrict__ sbits,
                      const unsigned* __restrict__ res,
                      const float* __restrict__ emb0,
                      const float* __restrict__ emb1,
                      float* __restrict__ out)
{
    const int b  = blockIdx.y;
    const int i0 = blockIdx.x << 4;
    const int t  = threadIdx.x;
    __shared__ float trans[16][CC + 4];

    const int c  = t >> 1;
    const int q8 = (t & 1) << 3;
    const unsigned* rp = res + ((size_t)((b << 7) | c) * TT) + i0 + q8;
    const unsigned* bw = sbits + ((size_t)((b << 7) | c)) * NW;
    const float e0 = emb0[c], e1 = emb1[c];

    #pragma unroll
    for (int jj = 0; jj < 8; ++jj) {
        const unsigned v = rp[jj];
        const int i = i0 + q8 + jj;
        float val = 0.0f;
        if (v >> 11) {
            const int d   = TT - (int)(v & 2047u);
            const int e1p = i - d + 1;
            val = ((bw[e1p >> 5] >> (e1p & 31)) & 1u) ? e1 : e0;
        }
        trans[q8 + jj][c] = val;
    }
    __syncthreads();

    const int ii = t >> 4;
    const int c0 = (t & 15) << 3;
    float4 w0 = *(const float4*)&trans[ii][c0];
    float4 w1 = *(const float4*)&trans[ii][c0 + 4];
    float* op = out + ((size_t)(b * TT + i0 + ii)) * CC + c0;
    *(float4*)op       = w0;
    *(float4*)(op + 4) = w1;
}

extern "C" void kernel_launch(void* const* d_in, const int* in_sizes, int n_in,
                              void* d_out, int out_size, void* d_ws, size_t ws_size,
                              hipStream_t stream)
{
    const float* x    = (const float*)d_in[0];
    const float* emb0 = (const float*)d_in[1];
    const float* emb1 = (const float*)d_in[2];
    float* out        = (float*)d_out;

    unsigned* sbits = (unsigned*)d_ws;                    // 128 KB
    unsigned* res   = (unsigned*)d_ws + SBITS_WORDS;      // 4 MB

    hipMemsetAsync((void*)res, 0, (size_t)RES_WORDS * 4, stream);
    k_bits<<<dim3(4 * 64), dim3(256), 0, stream>>>(x, sbits);
    k_dp2<<<dim3(36, NSEQ), dim3(256), 0, stream>>>(sbits, res);
    k_dec<<<dim3(TT / 16, 4), dim3(256), 0, stream>>>(sbits, res, emb0, emb1, out);
}

// Round 10
// 165.994 us; speedup vs baseline: 1.1880x; 1.0373x over previous
//
#include <hip/hip_runtime.h>

// ROSA 1-bit, B=4, T=2048, C=128 (512 sequences).
// Round 10: round-9 packed-SWAR algorithm (proven absmax 0), inner loop
// expressed in NATIVE clang ext-vector ops instead of inline asm.
// Theory: rounds 4-9 asm blocks forced v_accvgpr_read/write shuttles around
// every block (accumulators homed in AGPRs; "+v" constraints pin to arch
// VGPRs -> copies). Native VOP3P codegen (v_pk_ashrrev_i16 / v_pk_lshlrev_b16
// / v_pk_add_u16 / v_pk_max_u16 / v_bfi_b32) lets VALU ops execute directly
// on whatever file the allocator picks - no shuttles, free scheduling.

#define TT 2048
#define CC 128
#define NW 64
#define NSEQ 512
#define SBITS_WORDS (NSEQ * NW)       // 128 KB
#define RES_WORDS (NSEQ * TT)         // 4 MB, layout [q][i]

typedef short          s16x2 __attribute__((ext_vector_type(2)));
typedef unsigned short u16x2 __attribute__((ext_vector_type(2)));

__device__ __forceinline__ unsigned pk_sign(unsigned x) {   // per-half sign mask
    s16x2 v = __builtin_bit_cast(s16x2, x);
    v = v >> 15;
    return __builtin_bit_cast(unsigned, v);
}
__device__ __forceinline__ unsigned pk_shl1(unsigned x) {
    u16x2 v = __builtin_bit_cast(u16x2, x);
    v = v << 1;
    return __builtin_bit_cast(unsigned, v);
}
__device__ __forceinline__ unsigned pk_add8(unsigned x) {
    u16x2 v = __builtin_bit_cast(u16x2, x);
    v = v + (unsigned short)8;
    return __builtin_bit_cast(unsigned, v);
}
__device__ __forceinline__ unsigned pk_maxu(unsigned a, unsigned b) {
    u16x2 x = __builtin_bit_cast(u16x2, a);
    u16x2 y = __builtin_bit_cast(u16x2, b);
    u16x2 r = __builtin_elementwise_max(x, y);
    return __builtin_bit_cast(unsigned, r);
}

// ---------------- kernel 0: pack bits ----------------
__global__ void k_bits(const float* __restrict__ x, unsigned* __restrict__ sbits)
{
    const int b = blockIdx.x >> 6;
    const int w = blockIdx.x & 63;
    const int t = threadIdx.x;
    __shared__ unsigned char sbyt[32 * 132];

    #pragma unroll
    for (int r = 0; r < 16; ++r) {
        const int e  = t + (r << 8);
        const int ii = e >> 7;
        const int c  = e & 127;
        const float v = x[((size_t)(b * TT + (w << 5) + ii)) * CC + c];
        sbyt[ii * 132 + c] = (v > 0.0f) ? 1u : 0u;
    }
    __syncthreads();

    if (t < CC) {
        unsigned word = 0u;
        #pragma unroll
        for (int ii = 0; ii < 32; ++ii)
            word |= (unsigned)(sbyt[ii * 132 + t] & 1u) << ii;
        sbits[((b << 7) | t) * NW + w] = word;
    }
}

// ---------------- kernel 1: tiled diagonal DP (packed, native) ----------------
__global__ __launch_bounds__(256, 4) void k_dp2(
    const unsigned* __restrict__ sbits, unsigned* __restrict__ res)
{
    const int u = blockIdx.x;            // 0..35 (triangular (k, chunk))
    const int q = blockIdx.y;            // sequence = b*128 + c
    int k = 0;
    #pragma unroll
    for (int kk = 1; kk < 8; ++kk) if (u >= (kk * (kk + 1)) / 2) k = kk;
    const int chunk = u - (k * (k + 1)) / 2;
    const int D0 = 1 + (chunk << 8);

    const int tid  = threadIdx.x;
    const int lane = tid & 63;
    const int wv   = tid >> 6;
    const int g    = lane >> 3;          // stream in wave
    const int lm   = lane & 7;           // lane within stream
    const int wB   = k << 3;
    const int wloc = wB + lm;            // fixed output word of this lane
    const int kb   = k << 8;

    __shared__ unsigned pad[128];        // [0..63]=0, [64+w]=word w
    __shared__ unsigned seedl[256];      // incoming run at tile base per diagonal
    __shared__ unsigned wres[4][8][33];

    if (tid < 64) pad[tid] = 0u;
    else if (tid < 128) pad[tid] = sbits[q * NW + (tid - 64)];
    __syncthreads();

    // --- seed precompute: thread t -> diagonal D0+t ---
    {
        const int d = D0 + tid;
        unsigned acc = 0u;
        if (d < kb) {
            const int dw = d >> 5, dr = d & 31;
            for (int w = wB - 1; w >= 0; --w) {
                const int sw = w - dw;
                const unsigned u0 = pad[64 + sw];
                const unsigned u1 = pad[63 + sw];
                const unsigned shw = dr ? ((u0 << dr) | (u1 >> (32 - dr))) : u0;
                const unsigned ew = (sw > 0) ? 0xFFFFFFFFu
                                  : ((sw == 0) ? (0xFFFFFFFFu << dr) : 0u);
                const unsigned mw = (~(pad[64 + w] ^ shw)) & ew;
                const unsigned t2 = (mw == 0xFFFFFFFFu) ? 32u
                                  : (unsigned)__builtin_clz(~mw);
                acc += t2;
                if (t2 < 32u) break;
            }
        }
        seedl[tid] = acc;
    }
    __syncthreads();

    const unsigned a = pad[64 + wloc];

    unsigned lmaxp[16];
    #pragma unroll
    for (int j = 0; j < 16; ++j) lmaxp[j] = 0u;

    #pragma unroll
    for (int it = 0; it < 8; ++it) {
        const int d  = D0 + (it << 5) + (wv << 3) + g;
        const int dw = d >> 5;
        const int dr = d & 31;

        const int s = wloc - dw;
        const unsigned b0 = pad[64 + s];
        const unsigned b1 = pad[63 + s];
        const unsigned sh = dr ? ((b0 << dr) | (b1 >> (32 - dr))) : b0;
        const unsigned em = (s > 0) ? 0xFFFFFFFFu
                          : ((s == 0) ? (0xFFFFFFFFu << dr) : 0u);
        const unsigned m = (~(a ^ sh)) & em;

        // --- incoming run: seed for stream heads, clz fast path otherwise ---
        const unsigned seedv = seedl[(it << 5) + (wv << 3) + g];
        const unsigned pm = (unsigned)__shfl_up((int)m, 1, 64);
        const unsigned lead = (unsigned)__builtin_clz(~pm | 1u);
        unsigned inc = (lm == 0) ? seedv : lead;

        // exact rare fallback: some lane's previous word fully matched
        if (__builtin_expect(
                __ballot((lm > 0) && (pm == 0xFFFFFFFFu)) != 0ULL, 0)) {
            if ((lm > 0) && (pm == 0xFFFFFFFFu)) {
                unsigned acc = 0u;
                int w;
                for (w = wloc - 1; w >= wB; --w) {
                    const int sw = w - dw;
                    const unsigned u0 = pad[64 + sw];
                    const unsigned u1 = pad[63 + sw];
                    const unsigned shw = dr ? ((u0 << dr) | (u1 >> (32 - dr))) : u0;
                    const unsigned ew = (sw > 0) ? 0xFFFFFFFFu
                                      : ((sw == 0) ? (0xFFFFFFFFu << dr) : 0u);
                    const unsigned mw = (~(pad[64 + w] ^ shw)) & ew;
                    const unsigned t2 = (mw == 0xFFFFFFFFu) ? 32u
                                      : (unsigned)__builtin_clz(~mw);
                    acc += t2;
                    if (t2 < 32u) break;
                }
                if (w < wB) acc += seedv;
                inc = acc;
            }
        }

        // --- chain-B (bits 16..31) entry: run into bit 16, capped clz ---
        const unsigned nm   = ~m;
        const unsigned u16c = (unsigned)__builtin_clz((nm << 16) | 0x8000u);
        const unsigned s16  = u16c + ((u16c == 16u) ? inc : 0u);

        const unsigned itc  = 7u - (unsigned)it;
        const unsigned itc2 = itc * 0x10001u;
        unsigned rp = ((inc << 3) | itc) | (((s16 << 3) | itc) << 16);

        // mmr: chain A (m[15:0]) in lo half, chain B (m[31:16]) in hi half,
        // bit j at the sign position of each half after j left-shifts.
        const unsigned mr  = __builtin_bitreverse32(m);
        unsigned mmr = (mr >> 16) | (mr << 16);

        #pragma unroll
        for (int j = 0; j < 16; ++j) {
            const unsigned sm = pk_sign(mmr);        // v_pk_ashrrev_i16
            mmr = pk_shl1(mmr);                      // v_pk_lshlrev_b16
            rp  = pk_add8(rp);                       // v_pk_add_u16
            rp  = (rp & sm) | (itc2 & ~sm);          // v_bfi_b32
            lmaxp[j] = pk_maxu(lmaxp[j], rp);        // v_pk_max_u16
        }
    }

    // --- epilogue: expand packed (run<<3|itc) -> (run<<11)|dcode ---
    // dcode = 2048 - d = Kp + (itc<<5), Kp = 2048 - D0 - (wv<<3) - g - 224.
    unsigned lm32[32];
    const unsigned Kp = 2048u - (unsigned)(D0 + (wv << 3) + g) - 224u;
    #pragma unroll
    for (int j = 0; j < 16; ++j) {
        const unsigned v  = lmaxp[j];
        const unsigned lo = v & 0xFFFFu;
        const unsigned hi = v >> 16;
        lm32[j]      = ((lo & 0xFFF8u) << 8) + ((lo & 7u) << 5) + Kp;
        lm32[16 + j] = ((hi & 0xFFF8u) << 8) + ((hi & 7u) << 5) + Kp;
    }

    // --- reduce the 8 streams sharing each word ---
    #pragma unroll
    for (int bb = 0; bb < 32; ++bb) {
        unsigned v = lm32[bb];
        v = max(v, (unsigned)__shfl_xor((int)v, 8, 64));
        v = max(v, (unsigned)__shfl_xor((int)v, 16, 64));
        v = max(v, (unsigned)__shfl_xor((int)v, 32, 64));
        lm32[bb] = v;
    }
    if (lane < 8) {
        #pragma unroll
        for (int bb = 0; bb < 32; ++bb) wres[wv][lane][bb] = lm32[bb];
    }
    __syncthreads();

    // --- block merge + contiguous atomics into res[q][i] ---
    {
        const int lw = tid >> 5, bb = tid & 31;
        const unsigned v = max(max(wres[0][lw][bb], wres[1][lw][bb]),
                               max(wres[2][lw][bb], wres[3][lw][bb]));
        if (v >> 11) {
            const int i = ((wB + lw) << 5) + bb;
            atomicMax(&res[(size_t)q * TT + i], v);
        }
    }
}

// ---------------- kernel 2: decode (LDS transpose) ----------------
__global__ void k_dec(const unsigned* __restrict__ sbits,
                      const unsigned* __restrict__ res,
                      const float* __restrict__ emb0,
                      const float* __restrict__ emb1,
                      float* __restrict__ out)
{
    const int b  = blockIdx.y;
    const int i0 = blockIdx.x << 4;
    const int t  = threadIdx.x;
    __shared__ float trans[16][CC + 4];

    const int c  = t >> 1;
    const int q8 = (t & 1) << 3;
    const unsigned* rp = res + ((size_t)((b << 7) | c) * TT) + i0 + q8;
    const unsigned* bw = sbits + ((size_t)((b << 7) | c)) * NW;
    const float e0 = emb0[c], e1 = emb1[c];

    #pragma unroll
    for (int jj = 0; jj < 8; ++jj) {
        const unsigned v = rp[jj];
        const int i = i0 + q8 + jj;
        float val = 0.0f;
        if (v >> 11) {
            const int d   = TT - (int)(v & 2047u);
            const int e1p = i - d + 1;
            val = ((bw[e1p >> 5] >> (e1p & 31)) & 1u) ? e1 : e0;
        }
        trans[q8 + jj][c] = val;
    }
    __syncthreads();

    const int ii = t >> 4;
    const int c0 = (t & 15) << 3;
    float4 w0 = *(const float4*)&trans[ii][c0];
    float4 w1 = *(const float4*)&trans[ii][c0 + 4];
    float* op = out + ((size_t)(b * TT + i0 + ii)) * CC + c0;
    *(float4*)op       = w0;
    *(float4*)(op + 4) = w1;
}

extern "C" void kernel_launch(void* const* d_in, const int* in_sizes, int n_in,
                              void* d_out, int out_size, void* d_ws, size_t ws_size,
                              hipStream_t stream)
{
    const float* x    = (const float*)d_in[0];
    const float* emb0 = (const float*)d_in[1];
    const float* emb1 = (const float*)d_in[2];
    float* out        = (float*)d_out;

    unsigned* sbits = (unsigned*)d_ws;                    // 128 KB
    unsigned* res   = (unsigned*)d_ws + SBITS_WORDS;      // 4 MB

    hipMemsetAsync((void*)res, 0, (size_t)RES_WORDS * 4, stream);
    k_bits<<<dim3(4 * 64), dim3(256), 0, stream>>>(x, sbits);
    k_dp2<<<dim3(36, NSEQ), dim3(256), 0, stream>>>(sbits, res);
    k_dec<<<dim3(TT / 16, 4), dim3(256), 0, stream>>>(sbits, res, emb0, emb1, out);
}